// Round 10
// baseline (107.454 us; speedup 1.0000x reference)
//
#include <hip/hip_runtime.h>
#include <stdint.h>

typedef unsigned long long u64;
typedef unsigned int u32;
typedef __attribute__((ext_vector_type(8))) short bf16x8;
typedef __attribute__((ext_vector_type(4))) float f32x4;

__device__ __forceinline__ u64 fkey(float f, unsigned idx) {
    unsigned u = __float_as_uint(f);
    u = (u & 0x80000000u) ? ~u : (u | 0x80000000u);
    return ((u64)u << 32) | (u64)idx;
}
__device__ __forceinline__ u64 umin64(u64 a, u64 b) { return a < b ? a : b; }
__device__ __forceinline__ unsigned short f2bf(float f) {   // RNE fp32->bf16
    unsigned u = __float_as_uint(f);
    return (unsigned short)((u + 0x7FFFu + ((u >> 16) & 1u)) >> 16);
}
__device__ __forceinline__ float bf2f(unsigned short b) {
    return __uint_as_float((unsigned)b << 16);
}

#define BARRIER() asm volatile("s_barrier" ::: "memory")
#define FENCE()   asm volatile("" ::: "memory")
#define MFMA4(P, M, N, BB1, BB2)                                                                  \
    acc[P][M][N] = __builtin_amdgcn_mfma_f32_16x16x32_bf16(A1[M], BB1, acc[P][M][N], 0, 0, 0);    \
    acc[P][M][N] = __builtin_amdgcn_mfma_f32_16x16x32_bf16(A2[M], BB1, acc[P][M][N], 0, 0, 0);    \
    acc[P][M][N] = __builtin_amdgcn_mfma_f32_16x16x32_bf16(A1[M], BB2, acc[P][M][N], 0, 0, 0);    \
    acc[P][M][N] = __builtin_amdgcn_mfma_f32_16x16x32_bf16(A2[M], BB2, acc[P][M][N], 0, 0, 0);

// ---------------------------------------------------------------------------
// Kernel 1 (unchanged, proven): split x into bf16 planes, stored LINEAR:
// Xs[row][plane][chunk][col64]; col64 = par*32 + (colin&31),
// colin = (p*48+q)*4 + (j&3), chunk = colin>>5. Swizzle applied ONCE by gemm's
// per-lane global_load_lds source offset. Also xsum_lo/hi and scoreboard init.
// ---------------------------------------------------------------------------
extern "C" __global__ __launch_bounds__(256)
void prep_kernel(const float* __restrict__ x, unsigned short* __restrict__ Xs,
                 float* __restrict__ xsum, u64* __restrict__ sb) {
    __shared__ float xbuf[768];
    const int row = blockIdx.x;          // 0..255
    const int a = row >> 4, i = row & 15;
    for (int pass = 0; pass < 3; ++pass) {
        int t = pass * 256 + threadIdx.x;          // 0..767
        int g = t >> 3, j = t & 7;
        int p = g / 48, q = g - 48 * p;
        float v = x[((size_t)(a * 2 + p) * 126 + (19 + q)) * 128 + (i * 8 + j)];
        xbuf[t] = v;
        unsigned short b1 = f2bf(v);
        unsigned short b2 = f2bf(v - bf2f(b1));
        int par = (j >> 2);                        // 0 = lo, 1 = hi
        int colin = g * 4 + (j & 3);               // 0..383 within parity
        int c = colin >> 5;                        // chunk 0..11
        int col64 = par * 32 + (colin & 31);       // 0..63 within chunk-row
        size_t base = (size_t)row * 1536 + c * 64 + col64;
        Xs[base] = b1;            // plane 0 (x1)
        Xs[base + 768] = b2;      // plane 1 (x2)
    }
    __syncthreads();
    if (threadIdx.x < 2) {
        int off = threadIdx.x ? 4 : 0;
        float s = 0.f;
        for (int g = 0; g < 96; ++g)
            for (int j = 0; j < 4; ++j)
                s += xbuf[g * 8 + off + j];
        xsum[threadIdx.x * 256 + row] = s;
    }
    if (row == 0) {
        for (int t = threadIdx.x; t < 368; t += 256) sb[t] = ~0ULL;
    }
}

// ---------------------------------------------------------------------------
// Kernel 2: MFMA GEMM, r5-proven layout + m201-style 4-phase double-buffered
// schedule. Block = 64 ent x 256 rows, 512 thr (8 waves), grid 512, LDS 160KB
// (full dbuf) -> 1 block/CU. Per chunk: 4 phases, each {issue loads | ds_read
// cluster -> s_barrier -> 16-MFMA cluster} ; only ONE vmcnt(0) drain per chunk
// (end of Ph4), after all glds aged >=3 phases. cb reg-prefetch issued FIRST
// in the chunk so the compiler's auto-wait for the split leaves glds in
// flight. Raw s_barrier (asm, "memory") -- no per-phase vmcnt drain.
// LDS rows 128B of 8 16B granules; logical granule g of row r at g^(r&7).
// Epilogue: exact u64-key argmin -> LDS scoreboard -> 368 global atomicMin.
// ---------------------------------------------------------------------------
extern "C" __global__ __launch_bounds__(512, 2)
void gemm_kernel(const float* __restrict__ cb, const unsigned short* __restrict__ Xs,
                 const float* __restrict__ xsum, u64* __restrict__ sb) {
    __shared__ __align__(16) unsigned short cbt[2][128][64];   // 32KB
    __shared__ __align__(16) unsigned short xst[2][512][64];   // 128KB

    const int tid = threadIdx.x;
    const int lane = tid & 63;
    const int wid = tid >> 6;
    const int k0 = blockIdx.x * 64;
    const int eb = (wid & 1) * 32;      // wave entry base (within 64)
    const int rb = (wid >> 1) * 64;     // wave row base
    const int l15 = lane & 15;
    const int g4 = lane >> 4;
    const int h7 = lane & 7;

    // cb staging geometry (r5): e=tid>>4 (0..31), group sgl=(tid>>1)&7, half=tid&1
    const int se = tid >> 4;
    const int sgl = (tid >> 1) & 7;
    const int shalf = tid & 1;
    const int ssw = (((shalf * 32 + sgl * 4) >> 3) ^ (se & 7)) * 8 + (sgl & 1) * 4;

    // X source swizzle: source granule = (lane&7) ^ (ldsrow&7), ldsrow&7 == lane>>3
    const int gswz = h7 ^ (lane >> 3);

    f32x4 acc[2][2][4] = {};            // [parity][m][n]
    float sp0 = 0.f, sq0 = 0.f, sp1 = 0.f, sq1 = 0.f;
    float4 v1, v2;                      // cb prefetch regs
    bf16x8 A1[2], A2[2], B1[2], B2[2];

    const float* cbbase = cb + (size_t)(k0 + se) * 768 + sgl * 8 + shalf * 4;

    auto split_cb = [&](int buf) {
        sp0 += v1.x + v1.y + v1.z + v1.w;
        sq0 += v1.x * v1.x + v1.y * v1.y + v1.z * v1.z + v1.w * v1.w;
        sp1 += v2.x + v2.y + v2.z + v2.w;
        sq1 += v2.x * v2.x + v2.y * v2.y + v2.z * v2.z + v2.w * v2.w;
        unsigned short a1x = f2bf(v1.x), a1y = f2bf(v1.y), a1z = f2bf(v1.z), a1w = f2bf(v1.w);
        unsigned short a2x = f2bf(v2.x), a2y = f2bf(v2.y), a2z = f2bf(v2.z), a2w = f2bf(v2.w);
        *(ushort4*)&cbt[buf][se][ssw]      = make_ushort4(a1x, a1y, a1z, a1w);
        *(ushort4*)&cbt[buf][se + 64][ssw] = make_ushort4(f2bf(v1.x - bf2f(a1x)), f2bf(v1.y - bf2f(a1y)),
                                                          f2bf(v1.z - bf2f(a1z)), f2bf(v1.w - bf2f(a1w)));
        *(ushort4*)&cbt[buf][se + 32][ssw] = make_ushort4(a2x, a2y, a2z, a2w);
        *(ushort4*)&cbt[buf][se + 96][ssw] = make_ushort4(f2bf(v2.x - bf2f(a2x)), f2bf(v2.y - bf2f(a2y)),
                                                          f2bf(v2.z - bf2f(a2z)), f2bf(v2.w - bf2f(a2w)));
    };
    auto issue_x = [&](int buf, int c, int i0) {
#pragma unroll
        for (int i = 0; i < 4; ++i) {
            int lrow = (wid << 6) + ((i0 + i) << 3) + (lane >> 3);
            const unsigned short* gs = Xs + (size_t)(lrow & 255) * 1536 + (lrow >> 8) * 768
                                          + c * 64 + gswz * 8;
            __builtin_amdgcn_global_load_lds(
                (const __attribute__((address_space(1))) u32*)gs,
                (__attribute__((address_space(3))) u32*)&xst[buf][(wid << 6) + ((i0 + i) << 3)][0],
                16, 0, 0);
        }
    };

    // ---- prologue: stage chunk 0 into buf 0
    v1 = *(const float4*)cbbase;
    v2 = *(const float4*)(cbbase + 32 * 768);
    FENCE();
    issue_x(0, 0, 0);
    issue_x(0, 0, 4);
    FENCE();
    split_cb(0);
    asm volatile("s_waitcnt vmcnt(0) lgkmcnt(0)" ::: "memory");
    BARRIER();

    for (int c = 0; c < 12; ++c) {
        const int cur = c & 1, nxt = cur ^ 1;
        const bool pf = (c < 11);
        const int sws0 = ((g4 ^ h7) << 3);          // par0 granule
        const int sws1 = (((4 | g4) ^ h7) << 3);    // par1 granule

        // ======== Phase 1: cb(c+1) reg loads; glds half0; A+B(par0,n01); MFMA ========
        if (pf) {
            const float* s1 = cbbase + (c + 1) * 64;
            v1 = *(const float4*)s1;
            v2 = *(const float4*)(s1 + 32 * 768);
        }
        FENCE();
        if (pf) issue_x(nxt, c + 1, 0);
        FENCE();
        A1[0] = *(const bf16x8*)&cbt[cur][eb + l15][sws0];
        A1[1] = *(const bf16x8*)&cbt[cur][eb + 16 + l15][sws0];
        A2[0] = *(const bf16x8*)&cbt[cur][eb + 64 + l15][sws0];
        A2[1] = *(const bf16x8*)&cbt[cur][eb + 80 + l15][sws0];
        B1[0] = *(const bf16x8*)&xst[cur][rb + l15][sws0];
        B2[0] = *(const bf16x8*)&xst[cur][rb + 256 + l15][sws0];
        B1[1] = *(const bf16x8*)&xst[cur][rb + 16 + l15][sws0];
        B2[1] = *(const bf16x8*)&xst[cur][rb + 272 + l15][sws0];
        BARRIER();
        __builtin_amdgcn_s_setprio(1);
        MFMA4(0, 0, 0, B1[0], B2[0]) MFMA4(0, 1, 0, B1[0], B2[0])
        MFMA4(0, 0, 1, B1[1], B2[1]) MFMA4(0, 1, 1, B1[1], B2[1])
        __builtin_amdgcn_s_setprio(0);
        BARRIER();

        // ======== Phase 2: glds half1; B(par0,n23); MFMA ========
        if (pf) issue_x(nxt, c + 1, 4);
        FENCE();
        B1[0] = *(const bf16x8*)&xst[cur][rb + 32 + l15][sws0];
        B2[0] = *(const bf16x8*)&xst[cur][rb + 288 + l15][sws0];
        B1[1] = *(const bf16x8*)&xst[cur][rb + 48 + l15][sws0];
        B2[1] = *(const bf16x8*)&xst[cur][rb + 304 + l15][sws0];
        BARRIER();
        __builtin_amdgcn_s_setprio(1);
        MFMA4(0, 0, 2, B1[0], B2[0]) MFMA4(0, 1, 2, B1[0], B2[0])
        MFMA4(0, 0, 3, B1[1], B2[1]) MFMA4(0, 1, 3, B1[1], B2[1])
        __builtin_amdgcn_s_setprio(0);
        BARRIER();

        // ======== Phase 3: A+B(par1,n01); MFMA ========
        A1[0] = *(const bf16x8*)&cbt[cur][eb + l15][sws1];
        A1[1] = *(const bf16x8*)&cbt[cur][eb + 16 + l15][sws1];
        A2[0] = *(const bf16x8*)&cbt[cur][eb + 64 + l15][sws1];
        A2[1] = *(const bf16x8*)&cbt[cur][eb + 80 + l15][sws1];
        B1[0] = *(const bf16x8*)&xst[cur][rb + l15][sws1];
        B2[0] = *(const bf16x8*)&xst[cur][rb + 256 + l15][sws1];
        B1[1] = *(const bf16x8*)&xst[cur][rb + 16 + l15][sws1];
        B2[1] = *(const bf16x8*)&xst[cur][rb + 272 + l15][sws1];
        BARRIER();
        __builtin_amdgcn_s_setprio(1);
        MFMA4(1, 0, 0, B1[0], B2[0]) MFMA4(1, 1, 0, B1[0], B2[0])
        MFMA4(1, 0, 1, B1[1], B2[1]) MFMA4(1, 1, 1, B1[1], B2[1])
        __builtin_amdgcn_s_setprio(0);
        BARRIER();

        // ======== Phase 4: B(par1,n23); MFMA; split cb(c+1); single drain ========
        B1[0] = *(const bf16x8*)&xst[cur][rb + 32 + l15][sws1];
        B2[0] = *(const bf16x8*)&xst[cur][rb + 288 + l15][sws1];
        B1[1] = *(const bf16x8*)&xst[cur][rb + 48 + l15][sws1];
        B2[1] = *(const bf16x8*)&xst[cur][rb + 304 + l15][sws1];
        BARRIER();
        __builtin_amdgcn_s_setprio(1);
        MFMA4(1, 0, 2, B1[0], B2[0]) MFMA4(1, 1, 2, B1[0], B2[0])
        MFMA4(1, 0, 3, B1[1], B2[1]) MFMA4(1, 1, 3, B1[1], B2[1])
        __builtin_amdgcn_s_setprio(0);
        if (pf) split_cb(nxt);   // auto-wait covers only the 2 oldest (cb) loads
        asm volatile("s_waitcnt vmcnt(0) lgkmcnt(0)" ::: "memory");
        BARRIER();
    }

    // ---- finalize stats: reduce over group lanes (masks 2,4,8 keep parity bit0)
#pragma unroll
    for (int m = 2; m <= 8; m <<= 1) {
        sp0 += __shfl_xor(sp0, m); sq0 += __shfl_xor(sq0, m);
        sp1 += __shfl_xor(sp1, m); sq1 += __shfl_xor(sq1, m);
    }
    __syncthreads();                    // loop fully drained; cbt[0] dead
    float* stf = (float*)&cbt[0][0][0]; // [0..63]=csum_lo [64..]=csq_lo [128..]=csum_hi [192..]=csq_hi
    u64* msb = (u64*)((char*)&cbt[0][0][0] + 1024);   // 368-entry LDS scoreboard
    if ((tid & 15) < 2) {
        int par = tid & 1, e = tid >> 4;
        stf[par * 128 + e]           = sp0;
        stf[par * 128 + 64 + e]      = sq0;
        stf[par * 128 + e + 32]      = sp1;
        stf[par * 128 + 64 + e + 32] = sq1;
    }
    if (tid < 368) msb[tid] = ~0ULL;
    __syncthreads();

    // ---- scoring + argmin: D layout col(N=row)=lane&15, row(M)=(lane>>4)*4+reg
#pragma unroll
    for (int n = 0; n < 4; ++n) {
        const int r = rb + n * 16 + l15;
        const float xl = xsum[r], xh = xsum[256 + r];
        u64 kA = ~0ULL, kB = ~0ULL;
#pragma unroll
        for (int m = 0; m < 2; ++m) {
#pragma unroll
            for (int reg = 0; reg < 4; ++reg) {
                const int el = eb + m * 16 + (g4 << 2) + reg;
                const unsigned kg = (unsigned)(k0 + el);
                float stl = stf[el],       sql = stf[64 + el];
                float sth = stf[128 + el], sqh = stf[192 + el];
                float dl = acc[0][m][n][reg], dh = acc[1][m][n][reg];
                float lo_d = sql - 2.f * dl;
                float lo_m = (384.f - 2.f * stl + sql) - 2.f * (xl - dl);
                float hi_d = sqh - 2.f * dh;
                float hi_m = (384.f - 2.f * sth + sqh) - 2.f * (xh - dh);
                if (l15 < 7) {
                    kA = umin64(kA, umin64(fkey(lo_d, kg), fkey(lo_m, kg + 32768u)));
                    kB = umin64(kB, umin64(fkey(hi_d, kg), fkey(hi_m, kg + 32768u)));
                } else {
                    kA = umin64(kA, umin64(fkey(lo_d + hi_d, kg), fkey(lo_m + hi_m, kg + 32768u)));
                }
            }
        }
        kA = umin64(kA, __shfl_xor(kA, 16));
        kA = umin64(kA, __shfl_xor(kA, 32));
        kB = umin64(kB, __shfl_xor(kB, 16));
        kB = umin64(kB, __shfl_xor(kB, 32));
        if (lane < 16) {
            int a_ = r >> 4;
            if (l15 < 7) {
                atomicMin(&msb[a_ * 23 + l15], kA);
                atomicMin(&msb[a_ * 23 + 7 + l15], kB);
            } else {
                atomicMin(&msb[a_ * 23 + 14 + (l15 - 7)], kA);
            }
        }
    }
    __syncthreads();
    if (tid < 368) atomicMin(&sb[tid], msb[tid]);
}

// ---------------------------------------------------------------------------
// Kernel 3: emit bits. out[a][0:6]=0; bit b: stream s=b/22, bit bb=b%22.
// ---------------------------------------------------------------------------
extern "C" __global__ __launch_bounds__(512)
void bits_kernel(const u64* __restrict__ sb, float* __restrict__ out) {
    const int a = blockIdx.x;
    const int pos = threadIdx.x;   // 0..511
    float v = 0.f;
    if (pos >= 6) {
        int b = pos - 6;
        int s = b / 22;
        int bb = b - s * 22;
        unsigned idx = (unsigned)(sb[a * 23 + s] & 0xFFFFFFFFu);
        v = (float)((idx >> bb) & 1u);
    }
    out[a * 512 + pos] = v;
}

extern "C" void kernel_launch(void* const* d_in, const int* in_sizes, int n_in,
                              void* d_out, int out_size, void* d_ws, size_t ws_size,
                              hipStream_t stream) {
    const float* x  = (const float*)d_in[0];   // [16,2,126,128]
    const float* cb = (const float*)d_in[1];   // [32768,2,48,8]
    char* ws = (char*)d_ws;
    unsigned short* Xs = (unsigned short*)ws;              // 256*1536 bf16 = 768KB
    float* xsum        = (float*)(ws + 786432);            // 512 f32
    u64*   sb          = (u64*)(ws + 788480);              // 368 u64
    float* out = (float*)d_out;

    prep_kernel<<<256, 256, 0, stream>>>(x, Xs, xsum, sb);
    gemm_kernel<<<512, 512, 0, stream>>>(cb, Xs, xsum, sb);
    bits_kernel<<<16, 512, 0, stream>>>(sb, out);
}

// Round 11
// 81.718 us; speedup vs baseline: 1.3149x; 1.3149x over previous
//
#include <hip/hip_runtime.h>
#include <stdint.h>

typedef unsigned long long u64;
typedef unsigned int u32;
typedef __attribute__((ext_vector_type(8))) short bf16x8;
typedef __attribute__((ext_vector_type(4))) float f32x4;

__device__ __forceinline__ u64 fkey(float f, unsigned idx) {
    unsigned u = __float_as_uint(f);
    u = (u & 0x80000000u) ? ~u : (u | 0x80000000u);
    return ((u64)u << 32) | (u64)idx;
}
__device__ __forceinline__ u64 umin64(u64 a, u64 b) { return a < b ? a : b; }
__device__ __forceinline__ unsigned short f2bf(float f) {   // RNE fp32->bf16
    unsigned u = __float_as_uint(f);
    return (unsigned short)((u + 0x7FFFu + ((u >> 16) & 1u)) >> 16);
}
__device__ __forceinline__ float bf2f(unsigned short b) {
    return __uint_as_float((unsigned)b << 16);
}

// ---------------------------------------------------------------------------
// Kernel 1 (unchanged, proven): split x into bf16 planes, stored LINEAR:
// Xs[row][plane][chunk][col64]; col64 = par*32 + (colin&31),
// colin = (p*48+q)*4 + (j&3), chunk = colin>>5. Swizzle applied ONCE by gemm's
// per-lane global_load_lds source offset. Also xsum_lo/hi and scoreboard init.
// ---------------------------------------------------------------------------
extern "C" __global__ __launch_bounds__(256)
void prep_kernel(const float* __restrict__ x, unsigned short* __restrict__ Xs,
                 float* __restrict__ xsum, u64* __restrict__ sb) {
    __shared__ float xbuf[768];
    const int row = blockIdx.x;          // 0..255
    const int a = row >> 4, i = row & 15;
    for (int pass = 0; pass < 3; ++pass) {
        int t = pass * 256 + threadIdx.x;          // 0..767
        int g = t >> 3, j = t & 7;
        int p = g / 48, q = g - 48 * p;
        float v = x[((size_t)(a * 2 + p) * 126 + (19 + q)) * 128 + (i * 8 + j)];
        xbuf[t] = v;
        unsigned short b1 = f2bf(v);
        unsigned short b2 = f2bf(v - bf2f(b1));
        int par = (j >> 2);                        // 0 = lo, 1 = hi
        int colin = g * 4 + (j & 3);               // 0..383 within parity
        int c = colin >> 5;                        // chunk 0..11
        int col64 = par * 32 + (colin & 31);       // 0..63 within chunk-row
        size_t base = (size_t)row * 1536 + c * 64 + col64;
        Xs[base] = b1;            // plane 0 (x1)
        Xs[base + 768] = b2;      // plane 1 (x2)
    }
    __syncthreads();
    if (threadIdx.x < 2) {
        int off = threadIdx.x ? 4 : 0;
        float s = 0.f;
        for (int g = 0; g < 96; ++g)
            for (int j = 0; j < 4; ++j)
                s += xbuf[g * 8 + off + j];
        xsum[threadIdx.x * 256 + row] = s;
    }
    if (row == 0) {
        for (int t = threadIdx.x; t < 368; t += 256) sb[t] = ~0ULL;
    }
}

// ---------------------------------------------------------------------------
// Kernel 2: MFMA GEMM, r5 skeleton at 3 blocks/CU. Block = 64 ent x 128 rows,
// 256 threads (4 waves, wave tile 32e x 64r m2n4 -- identical to r5's wave
// code), grid 1024 (= 512 e-groups x 2 row-halves), LDS 48KB -> 3 blocks/CU.
// 2-barrier chunk loop (proven): stage cb (fp32 -> RNE split c1/c2 + stats,
// swizzled ds_write; r9-proven 4-entries/thread unit) + stage X via
// global_load_lds (per-lane pre-swizzled source) -> barrier -> MFMA -> barrier.
// SPLIT = 3 products (x1c1, x1c2, x2c1; x2c2 dropped: |err| <= 384*2^-20
// ~ 3.7e-4 << argmin gaps ~0.1): 25% less MFMA work.
// LDS rows 128B of 8 16B granules; logical granule g of row r at g^(r&7).
// Epilogue: exact u64-key argmin -> LDS scoreboard -> 368 global atomicMin.
// ---------------------------------------------------------------------------
extern "C" __global__ __launch_bounds__(256, 3)
void gemm_kernel(const float* __restrict__ cb, const unsigned short* __restrict__ Xs,
                 const float* __restrict__ xsum, u64* __restrict__ sb) {
    __shared__ __align__(16) unsigned short cbt[128][64];   // 16KB: c1 rows 0-63, c2 64-127
    __shared__ __align__(16) unsigned short xst[256][64];   // 32KB: x1 rows 0-127, x2 128-255

    const int tid = threadIdx.x;        // 0..255
    const int lane = tid & 63;
    const int wid = tid >> 6;           // 0..3
    const int eg = blockIdx.x >> 1;     // e-group 0..511
    const int rhalf = blockIdx.x & 1;   // row half
    const int k0 = eg * 64;
    const int eb = (wid & 1) * 32;      // wave entry base (within 64)
    const int rb = (wid >> 1) * 64;     // wave row base (within 128)
    const int l15 = lane & 15;
    const int g4 = lane >> 4;
    const int h7 = lane & 7;

    // cb staging unit (r9-proven): se0=tid>>4 (0..15), sgl=(tid>>1)&7, shalf=tid&1
    // entries se0, se0+32, se0+16, se0+48 (all share se0&7 -> same ssw)
    const int se0 = tid >> 4;
    const int sgl = (tid >> 1) & 7;
    const int shalf = tid & 1;
    const int ssw = (((shalf * 32 + sgl * 4) >> 3) ^ (se0 & 7)) * 8 + (sgl & 1) * 4;

    // X source swizzle: source granule = (lane&7) ^ (ldsrow&7), ldsrow&7 == lane>>3
    const int gswz = h7 ^ (lane >> 3);

    f32x4 acc[2][2][4] = {};            // [parity][m][n]
    float sp[4] = {0.f, 0.f, 0.f, 0.f}; // entries se0, se0+32, se0+16, se0+48 (parity shalf)
    float sq[4] = {0.f, 0.f, 0.f, 0.f};

    const float* cbbase = cb + (size_t)(k0 + se0) * 768 + sgl * 8 + shalf * 4;

    for (int c = 0; c < 12; ++c) {
        __syncthreads();
        // ---- stage cb: 4 entries x one parity-quad each -> split -> LDS
        {
            const float* s1 = cbbase + c * 64;
            float4 v1 = *(const float4*)s1;              // entry se0
            float4 v2 = *(const float4*)(s1 + 32 * 768); // entry se0+32
            float4 v3 = *(const float4*)(s1 + 16 * 768); // entry se0+16
            float4 v4 = *(const float4*)(s1 + 48 * 768); // entry se0+48
            sp[0] += v1.x + v1.y + v1.z + v1.w;
            sq[0] += v1.x * v1.x + v1.y * v1.y + v1.z * v1.z + v1.w * v1.w;
            sp[1] += v2.x + v2.y + v2.z + v2.w;
            sq[1] += v2.x * v2.x + v2.y * v2.y + v2.z * v2.z + v2.w * v2.w;
            sp[2] += v3.x + v3.y + v3.z + v3.w;
            sq[2] += v3.x * v3.x + v3.y * v3.y + v3.z * v3.z + v3.w * v3.w;
            sp[3] += v4.x + v4.y + v4.z + v4.w;
            sq[3] += v4.x * v4.x + v4.y * v4.y + v4.z * v4.z + v4.w * v4.w;
            unsigned short a1x = f2bf(v1.x), a1y = f2bf(v1.y), a1z = f2bf(v1.z), a1w = f2bf(v1.w);
            unsigned short a2x = f2bf(v2.x), a2y = f2bf(v2.y), a2z = f2bf(v2.z), a2w = f2bf(v2.w);
            unsigned short a3x = f2bf(v3.x), a3y = f2bf(v3.y), a3z = f2bf(v3.z), a3w = f2bf(v3.w);
            unsigned short a4x = f2bf(v4.x), a4y = f2bf(v4.y), a4z = f2bf(v4.z), a4w = f2bf(v4.w);
            *(ushort4*)&cbt[se0][ssw]       = make_ushort4(a1x, a1y, a1z, a1w);
            *(ushort4*)&cbt[se0 + 64][ssw]  = make_ushort4(f2bf(v1.x - bf2f(a1x)), f2bf(v1.y - bf2f(a1y)),
                                                           f2bf(v1.z - bf2f(a1z)), f2bf(v1.w - bf2f(a1w)));
            *(ushort4*)&cbt[se0 + 32][ssw]  = make_ushort4(a2x, a2y, a2z, a2w);
            *(ushort4*)&cbt[se0 + 96][ssw]  = make_ushort4(f2bf(v2.x - bf2f(a2x)), f2bf(v2.y - bf2f(a2y)),
                                                           f2bf(v2.z - bf2f(a2z)), f2bf(v2.w - bf2f(a2w)));
            *(ushort4*)&cbt[se0 + 16][ssw]  = make_ushort4(a3x, a3y, a3z, a3w);
            *(ushort4*)&cbt[se0 + 80][ssw]  = make_ushort4(f2bf(v3.x - bf2f(a3x)), f2bf(v3.y - bf2f(a3y)),
                                                           f2bf(v3.z - bf2f(a3z)), f2bf(v3.w - bf2f(a3w)));
            *(ushort4*)&cbt[se0 + 48][ssw]  = make_ushort4(a4x, a4y, a4z, a4w);
            *(ushort4*)&cbt[se0 + 112][ssw] = make_ushort4(f2bf(v4.x - bf2f(a4x)), f2bf(v4.y - bf2f(a4y)),
                                                           f2bf(v4.z - bf2f(a4z)), f2bf(v4.w - bf2f(a4w)));
        }
        // ---- stage X: 32KB via global_load_lds (per-lane swizzled source)
#pragma unroll
        for (int i = 0; i < 8; ++i) {
            int lrow = (wid << 6) + (i << 3) + (lane >> 3);   // 0..255
            const unsigned short* gs = Xs + (size_t)(rhalf * 128 + (lrow & 127)) * 1536
                                          + (lrow >> 7) * 768 + c * 64 + gswz * 8;
            __builtin_amdgcn_global_load_lds(
                (const __attribute__((address_space(1))) u32*)gs,
                (__attribute__((address_space(3))) u32*)&xst[(wid << 6) + (i << 3)][0],
                16, 0, 0);
        }
        __syncthreads();
        // ---- MFMA: per parity: m2 x n4 frags x 3 split products (K=32 each)
#pragma unroll
        for (int par = 0; par < 2; ++par) {
            const int sws = ((((par << 2) | g4) ^ h7) << 3);
            bf16x8 A1[2], A2[2];
#pragma unroll
            for (int m = 0; m < 2; ++m) {
                A1[m] = *(const bf16x8*)&cbt[eb + m * 16 + l15][sws];
                A2[m] = *(const bf16x8*)&cbt[eb + m * 16 + l15 + 64][sws];
            }
#pragma unroll
            for (int n = 0; n < 4; ++n) {
                const unsigned short* xr = &xst[rb + n * 16 + l15][sws];
                bf16x8 B1 = *(const bf16x8*)xr;
                bf16x8 B2 = *(const bf16x8*)(xr + 128 * 64);
#pragma unroll
                for (int m = 0; m < 2; ++m) {
                    acc[par][m][n] = __builtin_amdgcn_mfma_f32_16x16x32_bf16(A1[m], B1, acc[par][m][n], 0, 0, 0);
                    acc[par][m][n] = __builtin_amdgcn_mfma_f32_16x16x32_bf16(A2[m], B1, acc[par][m][n], 0, 0, 0);
                    acc[par][m][n] = __builtin_amdgcn_mfma_f32_16x16x32_bf16(A1[m], B2, acc[par][m][n], 0, 0, 0);
                }
            }
        }
    }

    // ---- finalize stats: reduce over group lanes (masks 2,4,8 keep parity bit0)
#pragma unroll
    for (int m = 2; m <= 8; m <<= 1)
#pragma unroll
        for (int s = 0; s < 4; ++s) {
            sp[s] += __shfl_xor(sp[s], m);
            sq[s] += __shfl_xor(sq[s], m);
        }
    __syncthreads();                    // all MFMA-phase ds_reads done; cbt dead
    float* stf = (float*)&cbt[0][0];    // [par*128 + {0:csum,64:csq} + ent]
    u64* msb = (u64*)((char*)&cbt[0][0] + 1024);   // 368-entry LDS scoreboard
    if ((tid & 15) < 2) {
        const int p = tid & 1;
        const int eo[4] = {0, 32, 16, 48};
#pragma unroll
        for (int s = 0; s < 4; ++s) {
            stf[p * 128 + se0 + eo[s]]      = sp[s];
            stf[p * 128 + 64 + se0 + eo[s]] = sq[s];
        }
    }
    for (int t = tid; t < 368; t += 256) msb[t] = ~0ULL;
    __syncthreads();

    // ---- scoring + argmin: D layout col(N=row)=lane&15, row(M)=(lane>>4)*4+reg
#pragma unroll
    for (int n = 0; n < 4; ++n) {
        const int r = rb + n * 16 + l15;          // 0..127 within block
        const int gr = rhalf * 128 + r;           // global row
        const float xl = xsum[gr], xh = xsum[256 + gr];
        u64 kA = ~0ULL, kB = ~0ULL;
#pragma unroll
        for (int m = 0; m < 2; ++m) {
#pragma unroll
            for (int reg = 0; reg < 4; ++reg) {
                const int el = eb + m * 16 + (g4 << 2) + reg;
                const unsigned kg = (unsigned)(k0 + el);
                float stl = stf[el],       sql = stf[64 + el];
                float sth = stf[128 + el], sqh = stf[192 + el];
                float dl = acc[0][m][n][reg], dh = acc[1][m][n][reg];
                float lo_d = sql - 2.f * dl;
                float lo_m = (384.f - 2.f * stl + sql) - 2.f * (xl - dl);
                float hi_d = sqh - 2.f * dh;
                float hi_m = (384.f - 2.f * sth + sqh) - 2.f * (xh - dh);
                if (l15 < 7) {
                    kA = umin64(kA, umin64(fkey(lo_d, kg), fkey(lo_m, kg + 32768u)));
                    kB = umin64(kB, umin64(fkey(hi_d, kg), fkey(hi_m, kg + 32768u)));
                } else {
                    kA = umin64(kA, umin64(fkey(lo_d + hi_d, kg), fkey(lo_m + hi_m, kg + 32768u)));
                }
            }
        }
        kA = umin64(kA, __shfl_xor(kA, 16));
        kA = umin64(kA, __shfl_xor(kA, 32));
        kB = umin64(kB, __shfl_xor(kB, 16));
        kB = umin64(kB, __shfl_xor(kB, 32));
        if (lane < 16) {
            int a_ = gr >> 4;
            if (l15 < 7) {
                atomicMin(&msb[a_ * 23 + l15], kA);
                atomicMin(&msb[a_ * 23 + 7 + l15], kB);
            } else {
                atomicMin(&msb[a_ * 23 + 14 + (l15 - 7)], kA);
            }
        }
    }
    __syncthreads();
    for (int t = tid; t < 368; t += 256) atomicMin(&sb[t], msb[t]);
}

// ---------------------------------------------------------------------------
// Kernel 3: emit bits. out[a][0:6]=0; bit b: stream s=b/22, bit bb=b%22.
// ---------------------------------------------------------------------------
extern "C" __global__ __launch_bounds__(512)
void bits_kernel(const u64* __restrict__ sb, float* __restrict__ out) {
    const int a = blockIdx.x;
    const int pos = threadIdx.x;   // 0..511
    float v = 0.f;
    if (pos >= 6) {
        int b = pos - 6;
        int s = b / 22;
        int bb = b - s * 22;
        unsigned idx = (unsigned)(sb[a * 23 + s] & 0xFFFFFFFFu);
        v = (float)((idx >> bb) & 1u);
    }
    out[a * 512 + pos] = v;
}

extern "C" void kernel_launch(void* const* d_in, const int* in_sizes, int n_in,
                              void* d_out, int out_size, void* d_ws, size_t ws_size,
                              hipStream_t stream) {
    const float* x  = (const float*)d_in[0];   // [16,2,126,128]
    const float* cb = (const float*)d_in[1];   // [32768,2,48,8]
    char* ws = (char*)d_ws;
    unsigned short* Xs = (unsigned short*)ws;              // 256*1536 bf16 = 768KB
    float* xsum        = (float*)(ws + 786432);            // 512 f32
    u64*   sb          = (u64*)(ws + 788480);              // 368 u64
    float* out = (float*)d_out;

    prep_kernel<<<256, 256, 0, stream>>>(x, Xs, xsum, sb);
    gemm_kernel<<<1024, 256, 0, stream>>>(cb, Xs, xsum, sb);
    bits_kernel<<<16, 512, 0, stream>>>(sb, out);
}

// Round 12
// 63.698 us; speedup vs baseline: 1.6869x; 1.2829x over previous
//
#include <hip/hip_runtime.h>
#include <stdint.h>

typedef unsigned long long u64;
typedef unsigned int u32;
typedef __attribute__((ext_vector_type(8))) short bf16x8;
typedef __attribute__((ext_vector_type(4))) float f32x4;

__device__ __forceinline__ u64 fkey(float f, unsigned idx) {
    unsigned u = __float_as_uint(f);
    u = (u & 0x80000000u) ? ~u : (u | 0x80000000u);
    return ((u64)u << 32) | (u64)idx;
}
__device__ __forceinline__ u64 umin64(u64 a, u64 b) { return a < b ? a : b; }
__device__ __forceinline__ unsigned short f2bf(float f) {   // RNE fp32->bf16
    unsigned u = __float_as_uint(f);
    return (unsigned short)((u + 0x7FFFu + ((u >> 16) & 1u)) >> 16);
}
__device__ __forceinline__ float bf2f(unsigned short b) {
    return __uint_as_float((unsigned)b << 16);
}

// ---------------------------------------------------------------------------
// Kernel 1 (unchanged, proven): split x into bf16 planes, stored LINEAR:
// Xs[row][plane][chunk][col64]; col64 = par*32 + (colin&31),
// colin = (p*48+q)*4 + (j&3), chunk = colin>>5. Granule swizzle applied ONCE,
// by gemm's per-lane global_load_lds source offset (rule 21).
// Also: xsum_lo/hi per row, and global scoreboard init.
// ---------------------------------------------------------------------------
extern "C" __global__ __launch_bounds__(256)
void prep_kernel(const float* __restrict__ x, unsigned short* __restrict__ Xs,
                 float* __restrict__ xsum, u64* __restrict__ sb) {
    __shared__ float xbuf[768];
    const int row = blockIdx.x;          // 0..255
    const int a = row >> 4, i = row & 15;
    for (int pass = 0; pass < 3; ++pass) {
        int t = pass * 256 + threadIdx.x;          // 0..767
        int g = t >> 3, j = t & 7;
        int p = g / 48, q = g - 48 * p;
        float v = x[((size_t)(a * 2 + p) * 126 + (19 + q)) * 128 + (i * 8 + j)];
        xbuf[t] = v;
        unsigned short b1 = f2bf(v);
        unsigned short b2 = f2bf(v - bf2f(b1));
        int par = (j >> 2);                        // 0 = lo, 1 = hi
        int colin = g * 4 + (j & 3);               // 0..383 within parity
        int c = colin >> 5;                        // chunk 0..11
        int col64 = par * 32 + (colin & 31);       // 0..63 within chunk-row
        size_t base = (size_t)row * 1536 + c * 64 + col64;
        Xs[base] = b1;            // plane 0 (x1)
        Xs[base + 768] = b2;      // plane 1 (x2)
    }
    __syncthreads();
    if (threadIdx.x < 2) {
        int off = threadIdx.x ? 4 : 0;
        float s = 0.f;
        for (int g = 0; g < 96; ++g)
            for (int j = 0; j < 4; ++j)
                s += xbuf[g * 8 + off + j];
        xsum[threadIdx.x * 256 + row] = s;
    }
    if (row == 0) {
        for (int t = threadIdx.x; t < 368; t += 256) sb[t] = ~0ULL;
    }
}

// ---------------------------------------------------------------------------
// Kernel 2: EXACT r5 structure (best measured: 69.8us total) with ONE change:
// 3-product split (x1c1, x2c1, x1c2; x2c2 dropped -- numerically validated
// in r11, added error <= 384*2^-20 ~ 3.7e-4 << argmin gaps). -25% MFMA work.
// Block = 64 ent x 256 rows, 512 thr, grid 512, 2 blocks/CU (LDS 80KB).
// 2-barrier chunk loop: stage cb (fp32 read once -> RNE split + stats,
// swizzled ds_write) + stage X via global_load_lds (pre-swizzled source)
// -> barrier -> MFMA -> barrier.
// LDS rows 128B of 8 16B granules; logical granule g of row r at g^(r&7).
// Epilogue: exact u64-key argmin -> LDS scoreboard -> 368 global atomicMin.
// ---------------------------------------------------------------------------
extern "C" __global__ __launch_bounds__(512, 4)
void gemm_kernel(const float* __restrict__ cb, const unsigned short* __restrict__ Xs,
                 const float* __restrict__ xsum, u64* __restrict__ sb) {
    __shared__ __align__(16) unsigned short cbt[128][64];   // 16KB
    __shared__ __align__(16) unsigned short xst[512][64];   // 64KB

    const int tid = threadIdx.x;
    const int lane = tid & 63;
    const int wid = tid >> 6;
    const int k0 = blockIdx.x * 64;
    const int eb = (wid & 1) * 32;      // wave entry base (within 64)
    const int rb = (wid >> 1) * 64;     // wave row base
    const int l15 = lane & 15;
    const int g4 = lane >> 4;
    const int h7 = lane & 7;

    // cb staging geometry: e=tid>>4 (0..31), group sgl=(tid>>1)&7, half=tid&1
    const int se = tid >> 4;
    const int sgl = (tid >> 1) & 7;
    const int shalf = tid & 1;
    const int scol = shalf * 32 + sgl * 4;
    const int ssw = (((scol >> 3) ^ (se & 7)) << 3) + (sgl & 1) * 4; // shorts

    // xs source swizzle: source granule = (lane&7) ^ (row&7), row&7 == lane>>3
    const int gswz = h7 ^ (lane >> 3);

    f32x4 acc[2][2][4] = {};            // [parity][m][n]
    float sp0 = 0.f, sq0 = 0.f, sp1 = 0.f, sq1 = 0.f;

    for (int c = 0; c < 12; ++c) {
        __syncthreads();
        // ---- stage cb: 64e x 8 groups x 16B fp32 -> split -> swizzled LDS
        const float* s1 = cb + (size_t)(k0 + se) * 768 + (c * 8 + sgl) * 8 + shalf * 4;
        float4 v1 = *(const float4*)s1;
        float4 v2 = *(const float4*)(s1 + 32 * 768);
        sp0 += v1.x + v1.y + v1.z + v1.w;
        sq0 += v1.x * v1.x + v1.y * v1.y + v1.z * v1.z + v1.w * v1.w;
        sp1 += v2.x + v2.y + v2.z + v2.w;
        sq1 += v2.x * v2.x + v2.y * v2.y + v2.z * v2.z + v2.w * v2.w;
        unsigned short a1x = f2bf(v1.x), a1y = f2bf(v1.y), a1z = f2bf(v1.z), a1w = f2bf(v1.w);
        unsigned short a2x = f2bf(v2.x), a2y = f2bf(v2.y), a2z = f2bf(v2.z), a2w = f2bf(v2.w);
        ushort4 c1a = make_ushort4(a1x, a1y, a1z, a1w);
        ushort4 c1b = make_ushort4(f2bf(v1.x - bf2f(a1x)), f2bf(v1.y - bf2f(a1y)),
                                   f2bf(v1.z - bf2f(a1z)), f2bf(v1.w - bf2f(a1w)));
        ushort4 c2a = make_ushort4(a2x, a2y, a2z, a2w);
        ushort4 c2b = make_ushort4(f2bf(v2.x - bf2f(a2x)), f2bf(v2.y - bf2f(a2y)),
                                   f2bf(v2.z - bf2f(a2z)), f2bf(v2.w - bf2f(a2w)));
        *(ushort4*)&cbt[se][ssw]      = c1a;   // rows se..se+96 share se&7
        *(ushort4*)&cbt[se + 64][ssw] = c1b;
        *(ushort4*)&cbt[se + 32][ssw] = c2a;
        *(ushort4*)&cbt[se + 96][ssw] = c2b;
        // ---- stage xs: 64KB via global_load_lds (per-lane swizzled source)
#pragma unroll
        for (int i = 0; i < 8; ++i) {
            int row = (wid << 6) + (i << 3) + (lane >> 3);
            const unsigned short* gs = Xs + (size_t)(row & 255) * 1536 + (row >> 8) * 768
                                          + c * 64 + gswz * 8;
            __builtin_amdgcn_global_load_lds(
                (const __attribute__((address_space(1))) u32*)gs,
                (__attribute__((address_space(3))) u32*)&xst[(wid << 6) + (i << 3)][0],
                16, 0, 0);
        }
        __syncthreads();
        // ---- MFMA: per parity: 2m x 4n frags x 3 split products (K=32 each)
#pragma unroll
        for (int par = 0; par < 2; ++par) {
            const int sws = ((((par << 2) | g4) ^ h7) << 3);
            bf16x8 A1[2], A2[2];
#pragma unroll
            for (int m = 0; m < 2; ++m) {
                A1[m] = *(const bf16x8*)&cbt[eb + m * 16 + l15][sws];
                A2[m] = *(const bf16x8*)&cbt[eb + m * 16 + l15 + 64][sws];
            }
#pragma unroll
            for (int n = 0; n < 4; ++n) {
                const unsigned short* xr = &xst[rb + n * 16 + l15][sws];
                bf16x8 B1 = *(const bf16x8*)xr;
                bf16x8 B2 = *(const bf16x8*)(xr + 256 * 64);
#pragma unroll
                for (int m = 0; m < 2; ++m) {
                    acc[par][m][n] = __builtin_amdgcn_mfma_f32_16x16x32_bf16(A1[m], B1, acc[par][m][n], 0, 0, 0);
                    acc[par][m][n] = __builtin_amdgcn_mfma_f32_16x16x32_bf16(A2[m], B1, acc[par][m][n], 0, 0, 0);
                    acc[par][m][n] = __builtin_amdgcn_mfma_f32_16x16x32_bf16(A1[m], B2, acc[par][m][n], 0, 0, 0);
                }
            }
        }
    }

    // ---- finalize stats: reduce over group lanes (masks 2,4,8 keep parity bit0)
#pragma unroll
    for (int m = 2; m <= 8; m <<= 1) {
        sp0 += __shfl_xor(sp0, m); sq0 += __shfl_xor(sq0, m);
        sp1 += __shfl_xor(sp1, m); sq1 += __shfl_xor(sq1, m);
    }
    __syncthreads();                    // all MFMA-phase ds_reads done; cbt dead
    float* stf = (float*)&cbt[0][0];    // [0..63]=csum_lo [64..]=csq_lo [128..]=csum_hi [192..]=csq_hi
    u64* msb = (u64*)((char*)&cbt[0][0] + 1024);   // 368-entry LDS scoreboard
    if ((tid & 15) < 2) {
        int par = tid & 1, e = tid >> 4;
        stf[par * 128 + e]           = sp0;
        stf[par * 128 + 64 + e]      = sq0;
        stf[par * 128 + e + 32]      = sp1;
        stf[par * 128 + 64 + e + 32] = sq1;
    }
    if (tid < 368) msb[tid] = ~0ULL;
    __syncthreads();

    // ---- scoring + argmin: D layout col(N=row)=lane&15, row(M)=(lane>>4)*4+reg
#pragma unroll
    for (int n = 0; n < 4; ++n) {
        const int r = rb + n * 16 + l15;
        const float xl = xsum[r], xh = xsum[256 + r];
        u64 kA = ~0ULL, kB = ~0ULL;
#pragma unroll
        for (int m = 0; m < 2; ++m) {
#pragma unroll
            for (int reg = 0; reg < 4; ++reg) {
                const int el = eb + m * 16 + (g4 << 2) + reg;
                const unsigned kg = (unsigned)(k0 + el);
                float stl = stf[el],       sql = stf[64 + el];
                float sth = stf[128 + el], sqh = stf[192 + el];
                float dl = acc[0][m][n][reg], dh = acc[1][m][n][reg];
                float lo_d = sql - 2.f * dl;
                float lo_m = (384.f - 2.f * stl + sql) - 2.f * (xl - dl);
                float hi_d = sqh - 2.f * dh;
                float hi_m = (384.f - 2.f * sth + sqh) - 2.f * (xh - dh);
                if (l15 < 7) {
                    kA = umin64(kA, umin64(fkey(lo_d, kg), fkey(lo_m, kg + 32768u)));
                    kB = umin64(kB, umin64(fkey(hi_d, kg), fkey(hi_m, kg + 32768u)));
                } else {
                    kA = umin64(kA, umin64(fkey(lo_d + hi_d, kg), fkey(lo_m + hi_m, kg + 32768u)));
                }
            }
        }
        kA = umin64(kA, __shfl_xor(kA, 16));
        kA = umin64(kA, __shfl_xor(kA, 32));
        kB = umin64(kB, __shfl_xor(kB, 16));
        kB = umin64(kB, __shfl_xor(kB, 32));
        if (lane < 16) {
            int a_ = r >> 4;
            if (l15 < 7) {
                atomicMin(&msb[a_ * 23 + l15], kA);
                atomicMin(&msb[a_ * 23 + 7 + l15], kB);
            } else {
                atomicMin(&msb[a_ * 23 + 14 + (l15 - 7)], kA);
            }
        }
    }
    __syncthreads();
    if (tid < 368) atomicMin(&sb[tid], msb[tid]);
}

// ---------------------------------------------------------------------------
// Kernel 3: emit bits. out[a][0:6]=0; bit b: stream s=b/22, bit bb=b%22.
// ---------------------------------------------------------------------------
extern "C" __global__ __launch_bounds__(512)
void bits_kernel(const u64* __restrict__ sb, float* __restrict__ out) {
    const int a = blockIdx.x;
    const int pos = threadIdx.x;   // 0..511
    float v = 0.f;
    if (pos >= 6) {
        int b = pos - 6;
        int s = b / 22;
        int bb = b - s * 22;
        unsigned idx = (unsigned)(sb[a * 23 + s] & 0xFFFFFFFFu);
        v = (float)((idx >> bb) & 1u);
    }
    out[a * 512 + pos] = v;
}

extern "C" void kernel_launch(void* const* d_in, const int* in_sizes, int n_in,
                              void* d_out, int out_size, void* d_ws, size_t ws_size,
                              hipStream_t stream) {
    const float* x  = (const float*)d_in[0];   // [16,2,126,128]
    const float* cb = (const float*)d_in[1];   // [32768,2,48,8]
    char* ws = (char*)d_ws;
    unsigned short* Xs = (unsigned short*)ws;              // 256*1536 bf16 = 768KB
    float* xsum        = (float*)(ws + 786432);            // 512 f32
    u64*   sb          = (u64*)(ws + 788480);              // 368 u64
    float* out = (float*)d_out;

    prep_kernel<<<256, 256, 0, stream>>>(x, Xs, xsum, sb);
    gemm_kernel<<<512, 512, 0, stream>>>(cb, Xs, xsum, sb);
    bits_kernel<<<16, 512, 0, stream>>>(sb, out);
}